// Round 13
// baseline (123.574 us; speedup 1.0000x reference)
//
#include <hip/hip_runtime.h>
#include <hip/hip_bf16.h>

// BERT self-attention, B=8 S=1024 D=768 H=12 DH=64, fp32 in/out.
// (1) proj v2 (unchanged R12): BM=64 BN=128, reg-prefetch + dbuf LDS ->
//     mixed + mixedT (per-head [d][tau(t)]).
// (2) attn v3: barrier-free L2-direct. No K/V/Q LDS staging (L2-resident,
//     T1-grouped); 32x32x16 swapped-QK MFMA; fixed-max softmax; split-KV x2
//     (wave pairs each do half of KV; merge = plain add thanks to fixed max).

#define D_MODEL 768
#define SEQ     1024
#define NHEAD   12
#define DHEAD   64
#define BATCH   8
#define QB      64
#define LOG2E   1.44269504088896f
#define FMLOG   28.8539008178f        /* 20 * log2(e) */
#define SCLC    (0.125f * LOG2E)

typedef __attribute__((ext_vector_type(8)))  short bf16x8;
typedef __attribute__((ext_vector_type(4)))  short short4v;
typedef __attribute__((ext_vector_type(4)))  float f32x4;
typedef __attribute__((ext_vector_type(16))) float f32x16;

__device__ __forceinline__ unsigned short f2bf(float f) {
  __hip_bfloat16 h = __float2bfloat16(f);
  return *reinterpret_cast<unsigned short*>(&h);
}

__device__ __forceinline__ float fexp2(float x) {
#if __has_builtin(__builtin_amdgcn_exp2f)
  return __builtin_amdgcn_exp2f(x);
#else
  return exp2f(x);
#endif
}

// swap bits 2<->3 of a t-index (the mixedT column permutation)
__device__ __forceinline__ int tau(int t) {
  return (t & ~0xC) | ((t & 8) >> 1) | ((t & 4) << 1);
}

// ---------------------------------------------------------------------------
// Projection GEMM v2 (unchanged from R12): mixed = bf16(X @ W^T + b);
// mixedT = [b][d][tau(t)].  BM=64 BN=128 BK=32; prefetch + dbuf.
// ---------------------------------------------------------------------------
template<bool WRITE_T>
__global__ __launch_bounds__(256) void proj_kernel(
    const float* __restrict__ X, const float* __restrict__ W,
    const float* __restrict__ bias, unsigned short* __restrict__ mixed,
    unsigned short* __restrict__ mixedT)
{
  __shared__ unsigned short As[2][64 * 40];    //  10 KB
  __shared__ unsigned short Bs[2][128 * 40];   //  20 KB

  const int tid = threadIdx.x;
  const int l   = tid & 63;
  const int w   = tid >> 6;
  const int m0  = blockIdx.x * 64;
  const int n0  = blockIdx.y * 128;
  const int wm  = (w >> 1) * 32;
  const int wn  = (w & 1) * 64;
  const int lr  = l & 15;
  const int g   = l >> 4;
  const int lk  = g * 8;

  const int ar = tid >> 2;            // A row 0..63
  const int ac = (tid & 3) * 8;       // col granule

  f32x4 a0, a1, b0[2], b1[2];
  auto loadSlab = [&](int k0) {
    const float* pa = &X[(size_t)(m0 + ar) * D_MODEL + k0 + ac];
    a0 = *(const f32x4*)pa;
    a1 = *(const f32x4*)(pa + 4);
    #pragma unroll
    for (int p = 0; p < 2; ++p) {
      const float* pb = &W[(size_t)(n0 + ar + p * 64) * D_MODEL + k0 + ac];
      b0[p] = *(const f32x4*)pb;
      b1[p] = *(const f32x4*)(pb + 4);
    }
  };
  auto stageSlab = [&](int bb) {
    bf16x8 av;
    #pragma unroll
    for (int jj = 0; jj < 4; ++jj) {
      av[jj]     = (short)f2bf(a0[jj]);
      av[4 + jj] = (short)f2bf(a1[jj]);
    }
    *(bf16x8*)&As[bb][ar * 40 + ac] = av;
    #pragma unroll
    for (int p = 0; p < 2; ++p) {
      bf16x8 bv;
      #pragma unroll
      for (int jj = 0; jj < 4; ++jj) {
        bv[jj]     = (short)f2bf(b0[p][jj]);
        bv[4 + jj] = (short)f2bf(b1[p][jj]);
      }
      *(bf16x8*)&Bs[bb][(ar + p * 64) * 40 + ac] = bv;
    }
  };

  f32x4 acc[2][4] = {};

  loadSlab(0);
  stageSlab(0);
  __syncthreads();

  int cur = 0;
  for (int k0 = 0; k0 < D_MODEL; k0 += 32) {
    const bool more = (k0 + 32 < D_MODEL);
    if (more) loadSlab(k0 + 32);

    bf16x8 af[2], bfr[4];
    #pragma unroll
    for (int am = 0; am < 2; ++am)
      af[am]  = *(const bf16x8*)&As[cur][(wm + am * 16 + lr) * 40 + lk];
    #pragma unroll
    for (int bn = 0; bn < 4; ++bn)
      bfr[bn] = *(const bf16x8*)&Bs[cur][(wn + bn * 16 + lr) * 40 + lk];

    #pragma unroll
    for (int am = 0; am < 2; ++am)
      #pragma unroll
      for (int bn = 0; bn < 4; ++bn)
        acc[am][bn] = __builtin_amdgcn_mfma_f32_16x16x32_bf16(
            af[am], bfr[bn], acc[am][bn], 0, 0, 0);

    if (more) {
      stageSlab(cur ^ 1);
      __syncthreads();
    }
    cur ^= 1;
  }

  const int orow = g * 4;
  const int bT   = m0 >> 10;
  const int tl0  = (m0 & 1023) + wm + orow;
  #pragma unroll
  for (int bn = 0; bn < 4; ++bn) {
    int   col  = n0 + wn + bn * 16 + lr;
    float bcol = bias[col];
    size_t tbase = ((size_t)bT * D_MODEL + col) * SEQ;
    #pragma unroll
    for (int am = 0; am < 2; ++am) {
      short4v pk;
      #pragma unroll
      for (int i = 0; i < 4; ++i) {
        float v = acc[am][bn][i] + bcol;
        unsigned short hv = f2bf(v);
        mixed[(size_t)(m0 + wm + am * 16 + orow + i) * D_MODEL + col] = hv;
        pk[i] = (short)hv;
      }
      if (WRITE_T)
        *(short4v*)&mixedT[tbase + tau(tl0 + am * 16)] = pk;
    }
  }
}

// ---------------------------------------------------------------------------
// attn v3: barrier-free L2-direct, split-KV x2.
// 256 thr = 4 waves: pair p = wave>>1 owns q-rows [q0+32p, q0+32p+32);
// half h = wave&1 processes KV [512h, 512h+512). Merge = plain add.
// ---------------------------------------------------------------------------
__global__ __launch_bounds__(256) void attn_kernel(
    const unsigned short* __restrict__ mixed,
    const unsigned short* __restrict__ mixedT,
    const float* __restrict__ mask, float* __restrict__ out)
{
  __shared__ float maskE[SEQ];        // 4 KB
  __shared__ float cbuf[2][64][33];   // 16.9 KB (padded: 2-way banks)
  __shared__ float lbuf[2][64];       // 512 B
  __shared__ float lb[64];            // 256 B
  __shared__ int   mflag;

  const int tid  = threadIdx.x;
  const int l    = tid & 63;
  const int wv   = tid >> 6;           // 0..3
  const int prq  = wv >> 1;            // q pair 0..1
  const int half = wv & 1;             // KV half
  const int l31  = l & 31;
  const int lh   = l >> 5;
  const int h4   = lh * 4;
  const int h8   = lh * 8;

  // T1: XCD-grouped decode — all 16 q-tiles of one (b,h) share id mod 8.
  const int id  = blockIdx.x;          // 0..1535
  const int xcd = id & 7;
  const int j   = id >> 3;             // 0..191
  const int pr  = xcd * 12 + (j >> 4); // (b,head), bijective over 96
  const int q0  = (j & 15) * QB;
  const int hd  = pr % NHEAD;
  const int b   = pr / NHEAD;

  const size_t base  = ((size_t)b * SEQ) * D_MODEL + hd * DHEAD;
  const size_t baseT = ((size_t)b * D_MODEL + hd * DHEAD) * SEQ;

  // ---- mask scan + exp2-domain fold (only LDS cooperation at init) ----
  if (tid == 0) mflag = 0;
  __syncthreads();
  {
    f32x4 mv = *(const f32x4*)&mask[(size_t)b * SEQ + tid * 4];
    #pragma unroll
    for (int jj = 0; jj < 4; ++jj)
      maskE[tid * 4 + jj] = fmaf(mv[jj], LOG2E, -FMLOG);
    if (mv[0] != 0.f || mv[1] != 0.f || mv[2] != 0.f || mv[3] != 0.f)
      mflag = 1;
  }
  __syncthreads();
  const bool hm = (mflag != 0);

  // ---- Q frags: direct global b128 (32 rows x 32B, one-time) ----
  const int qrow = q0 + prq * 32 + l31;
  bf16x8 qf[4];
  #pragma unroll
  for (int db = 0; db < 4; ++db)
    qf[db] = *(const bf16x8*)&mixed[base + (size_t)qrow * D_MODEL + db * 16 + h8];

  f32x16 c0 = {}, c1 = {};
  float lsum = 0.f;
  const int kv0 = half * (SEQ / 2);

  for (int t0 = kv0; t0 < kv0 + SEQ / 2; t0 += 64) {
    #pragma unroll
    for (int sub = 0; sub < 2; ++sub) {
      const int tr = t0 + sub * 32;

      // ---- S^T subtile = K[tr..tr+31] @ Q^T : 4 MFMA, K direct from L2 ----
      f32x16 s = {};
      #pragma unroll
      for (int db = 0; db < 4; ++db) {
        bf16x8 kf = *(const bf16x8*)&mixed[base +
                      (size_t)(tr + l31) * D_MODEL + db * 16 + h8];
        s = __builtin_amdgcn_mfma_f32_32x32x16_bf16(kf, qf[db], s, 0, 0, 0);
      }

      // ---- softmax-lite (fixed max) ----
      float p[16];
      if (hm) {
        #pragma unroll
        for (int r = 0; r < 16; ++r) {
          int kvr = (r & 3) + 8 * (r >> 2) + h4;
          p[r] = fexp2(fmaf(s[r], SCLC, maskE[tr + kvr]));
          lsum += p[r];
        }
      } else {
        #pragma unroll
        for (int r = 0; r < 16; ++r) {
          p[r] = fexp2(fmaf(s[r], SCLC, -FMLOG));
          lsum += p[r];
        }
      }

      // ---- PV: pack A-frags, V direct from mixedT (tau baked in) ----
      #pragma unroll
      for (int f = 0; f < 2; ++f) {
        bf16x8 pa;
        #pragma unroll
        for (int jj = 0; jj < 8; ++jj) pa[jj] = (short)f2bf(p[8 * f + jj]);
        const size_t vcol = tr + f * 16 + h8;
        bf16x8 v0 = *(const bf16x8*)&mixedT[baseT + (size_t)l31 * SEQ + vcol];
        bf16x8 v1 = *(const bf16x8*)&mixedT[baseT + (size_t)(32 + l31) * SEQ + vcol];
        c0 = __builtin_amdgcn_mfma_f32_32x32x16_bf16(pa, v0, c0, 0, 0, 0);
        c1 = __builtin_amdgcn_mfma_f32_32x32x16_bf16(pa, v1, c1, 0, 0, 0);
      }
    }
  }

  // ---- split-KV merge: fixed-max sums combine by plain addition ----
  float l_tot = lsum + __shfl_xor(lsum, 32);
  if (half == 1) {
    #pragma unroll
    for (int r = 0; r < 16; ++r) {
      cbuf[prq][l][r]      = c0[r];
      cbuf[prq][l][16 + r] = c1[r];
    }
    lbuf[prq][l] = l_tot;
  }
  __syncthreads();

  if (half == 0) {
    #pragma unroll
    for (int r = 0; r < 16; ++r) {
      c0[r] += cbuf[prq][l][r];
      c1[r] += cbuf[prq][l][16 + r];
    }
    l_tot += lbuf[prq][l];

    if (lh == 0) lb[prq * 32 + l31] = l_tot;
    // same-wave LDS read below; compiler inserts the wait

    #pragma unroll
    for (int r = 0; r < 16; ++r) {
      int qr = (r & 3) + 8 * (r >> 2) + h4;
      float linv = __builtin_amdgcn_rcpf(lb[prq * 32 + qr]);
      int row = q0 + prq * 32 + qr;
      float* orow = &out[((size_t)b * SEQ + row) * D_MODEL + hd * DHEAD];
      orow[l31]      = c0[r] * linv;
      orow[32 + l31] = c1[r] * linv;
    }
  }
}

// ---------------------------------------------------------------------------
extern "C" void kernel_launch(void* const* d_in, const int* in_sizes, int n_in,
                              void* d_out, int out_size, void* d_ws, size_t ws_size,
                              hipStream_t stream) {
  const float* x    = (const float*)d_in[0];
  const float* mask = (const float*)d_in[1];
  const float* W    = (const float*)d_in[2];
  const float* bias = (const float*)d_in[3];
  float* out        = (float*)d_out;

  const size_t NM = (size_t)8192 * D_MODEL;
  unsigned short* mixed  = (unsigned short*)d_ws;          // 12.58 MB
  unsigned short* mixedT = mixed + NM;                      // 12.58 MB

  dim3 gp(8192 / 64, D_MODEL / 128);                // (128, 6) = 768 blocks
  const int nblk = (SEQ / QB) * NHEAD * BATCH;      // 1536 = 8 * 192

  proj_kernel<true><<<gp, 256, 0, stream>>>(x, W, bias, mixed, mixedT);
  attn_kernel<<<nblk, 256, 0, stream>>>(mixed, mixedT, mask, out);
}

// Round 14
// 68.750 us; speedup vs baseline: 1.7974x; 1.7974x over previous
//
#include <hip/hip_runtime.h>
#include <hip/hip_bf16.h>

// BERT self-attention, B=8 S=1024 D=768 H=12 DH=64, fp32 in/out.
// (1) proj v2 (unchanged R12): BM=64 BN=128, reg-prefetch + dbuf LDS ->
//     mixed + mixedT (per-head [d][tau(t)]).
// (2) attn v4: 512 thr = 8 waves; wave pair owns 32 q-rows, halves split each
//     KV tile (32 rows each). LDS-staged dbuf KV (1 barrier/tile), swapped-QK
//     32x32x16 MFMA, fixed-max softmax, add-merge in retired KV LDS.

#define D_MODEL 768
#define SEQ     1024
#define NHEAD   12
#define DHEAD   64
#define BATCH   8
#define QB      128
#define LOG2E   1.44269504088896f
#define FMLOG   28.8539008178f        /* 20 * log2(e) */
#define SCLC    (0.125f * LOG2E)

typedef __attribute__((ext_vector_type(8)))  short bf16x8;
typedef __attribute__((ext_vector_type(4)))  short short4v;
typedef __attribute__((ext_vector_type(2)))  float f32x2;
typedef __attribute__((ext_vector_type(4)))  float f32x4;
typedef __attribute__((ext_vector_type(16))) float f32x16;

__device__ __forceinline__ unsigned short f2bf(float f) {
  __hip_bfloat16 h = __float2bfloat16(f);
  return *reinterpret_cast<unsigned short*>(&h);
}

__device__ __forceinline__ float fexp2(float x) {
#if __has_builtin(__builtin_amdgcn_exp2f)
  return __builtin_amdgcn_exp2f(x);
#else
  return exp2f(x);
#endif
}

// 64-wide bf16 tile: elem-index XOR swizzle (16B granule x row)
__device__ __forceinline__ int lswz(int r, int c) {
  return (r << 6) + (c ^ ((r & 7) << 3));
}
// swap bits 2<->3 of a t-index (the mixedT column permutation)
__device__ __forceinline__ int tau(int t) {
  return (t & ~0xC) | ((t & 8) >> 1) | ((t & 4) << 1);
}

// ---------------------------------------------------------------------------
// Projection GEMM v2 (unchanged from R12): mixed = bf16(X @ W^T + b);
// mixedT = [b][d][tau(t)].  BM=64 BN=128 BK=32; prefetch + dbuf.
// ---------------------------------------------------------------------------
template<bool WRITE_T>
__global__ __launch_bounds__(256) void proj_kernel(
    const float* __restrict__ X, const float* __restrict__ W,
    const float* __restrict__ bias, unsigned short* __restrict__ mixed,
    unsigned short* __restrict__ mixedT)
{
  __shared__ unsigned short As[2][64 * 40];    //  10 KB
  __shared__ unsigned short Bs[2][128 * 40];   //  20 KB

  const int tid = threadIdx.x;
  const int l   = tid & 63;
  const int w   = tid >> 6;
  const int m0  = blockIdx.x * 64;
  const int n0  = blockIdx.y * 128;
  const int wm  = (w >> 1) * 32;
  const int wn  = (w & 1) * 64;
  const int lr  = l & 15;
  const int g   = l >> 4;
  const int lk  = g * 8;

  const int ar = tid >> 2;            // A row 0..63
  const int ac = (tid & 3) * 8;       // col granule

  f32x4 a0, a1, b0[2], b1[2];
  auto loadSlab = [&](int k0) {
    const float* pa = &X[(size_t)(m0 + ar) * D_MODEL + k0 + ac];
    a0 = *(const f32x4*)pa;
    a1 = *(const f32x4*)(pa + 4);
    #pragma unroll
    for (int p = 0; p < 2; ++p) {
      const float* pb = &W[(size_t)(n0 + ar + p * 64) * D_MODEL + k0 + ac];
      b0[p] = *(const f32x4*)pb;
      b1[p] = *(const f32x4*)(pb + 4);
    }
  };
  auto stageSlab = [&](int bb) {
    bf16x8 av;
    #pragma unroll
    for (int jj = 0; jj < 4; ++jj) {
      av[jj]     = (short)f2bf(a0[jj]);
      av[4 + jj] = (short)f2bf(a1[jj]);
    }
    *(bf16x8*)&As[bb][ar * 40 + ac] = av;
    #pragma unroll
    for (int p = 0; p < 2; ++p) {
      bf16x8 bv;
      #pragma unroll
      for (int jj = 0; jj < 4; ++jj) {
        bv[jj]     = (short)f2bf(b0[p][jj]);
        bv[4 + jj] = (short)f2bf(b1[p][jj]);
      }
      *(bf16x8*)&Bs[bb][(ar + p * 64) * 40 + ac] = bv;
    }
  };

  f32x4 acc[2][4] = {};

  loadSlab(0);
  stageSlab(0);
  __syncthreads();

  int cur = 0;
  for (int k0 = 0; k0 < D_MODEL; k0 += 32) {
    const bool more = (k0 + 32 < D_MODEL);
    if (more) loadSlab(k0 + 32);

    bf16x8 af[2], bfr[4];
    #pragma unroll
    for (int am = 0; am < 2; ++am)
      af[am]  = *(const bf16x8*)&As[cur][(wm + am * 16 + lr) * 40 + lk];
    #pragma unroll
    for (int bn = 0; bn < 4; ++bn)
      bfr[bn] = *(const bf16x8*)&Bs[cur][(wn + bn * 16 + lr) * 40 + lk];

    #pragma unroll
    for (int am = 0; am < 2; ++am)
      #pragma unroll
      for (int bn = 0; bn < 4; ++bn)
        acc[am][bn] = __builtin_amdgcn_mfma_f32_16x16x32_bf16(
            af[am], bfr[bn], acc[am][bn], 0, 0, 0);

    if (more) {
      stageSlab(cur ^ 1);
      __syncthreads();
    }
    cur ^= 1;
  }

  const int orow = g * 4;
  const int bT   = m0 >> 10;
  const int tl0  = (m0 & 1023) + wm + orow;
  #pragma unroll
  for (int bn = 0; bn < 4; ++bn) {
    int   col  = n0 + wn + bn * 16 + lr;
    float bcol = bias[col];
    size_t tbase = ((size_t)bT * D_MODEL + col) * SEQ;
    #pragma unroll
    for (int am = 0; am < 2; ++am) {
      short4v pk;
      #pragma unroll
      for (int i = 0; i < 4; ++i) {
        float v = acc[am][bn][i] + bcol;
        unsigned short hv = f2bf(v);
        mixed[(size_t)(m0 + wm + am * 16 + orow + i) * D_MODEL + col] = hv;
        pk[i] = (short)hv;
      }
      if (WRITE_T)
        *(short4v*)&mixedT[tbase + tau(tl0 + am * 16)] = pk;
    }
  }
}

// ---------------------------------------------------------------------------
// attn v4: 512 thr = 8 waves; pair (wv>>1) owns q rows [pair*32,+32);
// half (wv&1) processes kv subtile half*32 of each 64-tile.
// ---------------------------------------------------------------------------
__global__ __launch_bounds__(512) void attn_kernel(
    const unsigned short* __restrict__ mixed,
    const unsigned short* __restrict__ mixedT,
    const float* __restrict__ mask, float* __restrict__ out)
{
  __shared__ unsigned short kvbuf[2][2][4096];  // 32 KB [dbuf][K|V][64x64]
  __shared__ float maskE[SEQ];                  //  4 KB
  __shared__ float lbuf[4][64];                 //  1 KB
  __shared__ float lb[128];                     // 512 B
  __shared__ int   mflag;

  const int tid  = threadIdx.x;
  const int l    = tid & 63;
  const int wv   = tid >> 6;           // 0..7
  const int prq  = wv >> 1;            // q pair 0..3
  const int half = wv & 1;             // kv subtile
  const int l31  = l & 31;
  const int lh   = l >> 5;
  const int h4   = lh * 4;
  const int h8   = lh * 8;

  // T1: XCD-grouped decode — all 8 q-tiles of one (b,h) share id mod 8.
  const int id  = blockIdx.x;          // 0..767
  const int xcd = id & 7;
  const int j   = id >> 3;             // 0..95
  const int pr  = xcd * 12 + (j >> 3); // (b,head), bijective over 96
  const int q0  = (j & 7) * QB;
  const int hd  = pr % NHEAD;
  const int b   = pr / NHEAD;

  const size_t base  = ((size_t)b * SEQ) * D_MODEL + hd * DHEAD;
  const size_t baseT = ((size_t)b * D_MODEL + hd * DHEAD) * SEQ;

  const int r0 = tid >> 3;             // 0..63 staging row (1 pass)
  const int sc = (tid & 7) * 8;        // staging col granule

  // ---- mask scan + exp2-domain fold ----
  if (tid == 0) mflag = 0;
  __syncthreads();
  {
    f32x2 mv = *(const f32x2*)&mask[(size_t)b * SEQ + tid * 2];
    maskE[tid * 2]     = fmaf(mv[0], LOG2E, -FMLOG);
    maskE[tid * 2 + 1] = fmaf(mv[1], LOG2E, -FMLOG);
    if (mv[0] != 0.f || mv[1] != 0.f) mflag = 1;
  }

  // ---- stage Q (128x64) into kvbuf flat (16 KB) ----
  unsigned short* QQ = &kvbuf[0][0][0];
  #pragma unroll
  for (int pp = 0; pp < 2; ++pp) {
    int g   = tid + pp * 512;
    int row = g >> 3;
    int c   = (g & 7) * 8;
    *(bf16x8*)&QQ[lswz(row, c)] =
        *(const bf16x8*)&mixed[base + (size_t)(q0 + row) * D_MODEL + c];
  }
  __syncthreads();

  const bool hm = (mflag != 0);
  bf16x8 qf[4];
  #pragma unroll
  for (int db = 0; db < 4; ++db)
    qf[db] = *(const bf16x8*)&QQ[lswz(prq * 32 + l31, db * 16 + h8)];
  __syncthreads();                     // Q reads done before kv0 overwrites

  // ---- staging helpers: 1 K granule + 1 V granule per thread ----
  bf16x8 kr, tr;
  auto loadKV = [&](int tt) {
    kr = *(const bf16x8*)&mixed[base + (size_t)(tt + r0) * D_MODEL + sc];
    tr = *(const bf16x8*)&mixedT[baseT + (size_t)r0 * SEQ + tt + sc];
  };
  auto stageKV = [&](int bb) {
    *(bf16x8*)&kvbuf[bb][0][lswz(r0, sc)] = kr;
    *(bf16x8*)&kvbuf[bb][1][lswz(r0, sc)] = tr;
  };

  loadKV(0);
  stageKV(0);
  __syncthreads();

  f32x16 c0 = {}, c1 = {};
  float lsum = 0.f;
  int cur = 0;
  const int sr = half * 32;            // this wave's kv subtile offset

  for (int t0 = 0; t0 < SEQ; t0 += 64) {
    const bool more = (t0 + 64 < SEQ);
    if (more) loadKV(t0 + 64);         // T14: issue next tile's loads early

    // ---- S^T subtile = K[sr..sr+31] @ Q^T : 4 MFMA ----
    f32x16 s = {};
    #pragma unroll
    for (int db = 0; db < 4; ++db) {
      bf16x8 kf = *(const bf16x8*)&kvbuf[cur][0][lswz(sr + l31, db * 16 + h8)];
      s = __builtin_amdgcn_mfma_f32_32x32x16_bf16(kf, qf[db], s, 0, 0, 0);
    }

    // ---- softmax-lite (fixed max) ----
    float p[16];
    if (hm) {
      #pragma unroll
      for (int r = 0; r < 16; ++r) {
        int kvr = (r & 3) + 8 * (r >> 2) + h4;
        p[r] = fexp2(fmaf(s[r], SCLC, maskE[t0 + sr + kvr]));
        lsum += p[r];
      }
    } else {
      #pragma unroll
      for (int r = 0; r < 16; ++r) {
        p[r] = fexp2(fmaf(s[r], SCLC, -FMLOG));
        lsum += p[r];
      }
    }

    // ---- PV: pack A-frags, V from staged tile ----
    #pragma unroll
    for (int f = 0; f < 2; ++f) {
      bf16x8 pa;
      #pragma unroll
      for (int jj = 0; jj < 8; ++jj) pa[jj] = (short)f2bf(p[8 * f + jj]);
      const int cc = sr + f * 16 + h8;
      bf16x8 v0 = *(const bf16x8*)&kvbuf[cur][1][lswz(l31, cc)];
      bf16x8 v1 = *(const bf16x8*)&kvbuf[cur][1][lswz(32 + l31, cc)];
      c0 = __builtin_amdgcn_mfma_f32_32x32x16_bf16(pa, v0, c0, 0, 0, 0);
      c1 = __builtin_amdgcn_mfma_f32_32x32x16_bf16(pa, v1, c1, 0, 0, 0);
    }

    if (more) {
      stageKV(cur ^ 1);
      __syncthreads();
    }
    cur ^= 1;
  }

  // ---- cross-half merge (fixed max => plain add) in retired KV LDS ----
  float l_tot = lsum + __shfl_xor(lsum, 32);
  __syncthreads();                     // all kvbuf reads done; safe to alias
  float* mg = (float*)&kvbuf[0][0][0]; // [4][32][64] floats = 32 KB

  if (half == 1) {
    #pragma unroll
    for (int r = 0; r < 16; ++r) {
      mg[(prq * 32 + r) * 64 + l]      = c0[r];
      mg[(prq * 32 + 16 + r) * 64 + l] = c1[r];
    }
    lbuf[prq][l] = l_tot;
  }
  __syncthreads();

  if (half == 0) {
    #pragma unroll
    for (int r = 0; r < 16; ++r) {
      c0[r] += mg[(prq * 32 + r) * 64 + l];
      c1[r] += mg[(prq * 32 + 16 + r) * 64 + l];
    }
    l_tot += lbuf[prq][l];

    if (lh == 0) lb[prq * 32 + l31] = l_tot;
    // same-wave LDS read below; compiler inserts the wait

    #pragma unroll
    for (int r = 0; r < 16; ++r) {
      int qr = (r & 3) + 8 * (r >> 2) + h4;
      float linv = __builtin_amdgcn_rcpf(lb[prq * 32 + qr]);
      int row = q0 + prq * 32 + qr;
      float* orow = &out[((size_t)b * SEQ + row) * D_MODEL + hd * DHEAD];
      orow[l31]      = c0[r] * linv;
      orow[32 + l31] = c1[r] * linv;
    }
  }
}

// ---------------------------------------------------------------------------
extern "C" void kernel_launch(void* const* d_in, const int* in_sizes, int n_in,
                              void* d_out, int out_size, void* d_ws, size_t ws_size,
                              hipStream_t stream) {
  const float* x    = (const float*)d_in[0];
  const float* mask = (const float*)d_in[1];
  const float* W    = (const float*)d_in[2];
  const float* bias = (const float*)d_in[3];
  float* out        = (float*)d_out;

  const size_t NM = (size_t)8192 * D_MODEL;
  unsigned short* mixed  = (unsigned short*)d_ws;          // 12.58 MB
  unsigned short* mixedT = mixed + NM;                      // 12.58 MB

  dim3 gp(8192 / 64, D_MODEL / 128);                // (128, 6) = 768 blocks
  const int nblk = (SEQ / QB) * NHEAD * BATCH;      // 768 = 8 * 96

  proj_kernel<true><<<gp, 256, 0, stream>>>(x, W, bias, mixed, mixedT);
  attn_kernel<<<nblk, 512, 0, stream>>>(mixed, mixedT, mask, out);
}